// Round 4
// baseline (1342.338 us; speedup 1.0000x reference)
//
#include <hip/hip_runtime.h>
#include <stdint.h>

// ---------------------------------------------------------------------------
// RPN FPN head, MI355X (gfx950).  Two launches total:
//  prep_all : zero pad rings + repack weights + NCHW->padded-NHWC bf16 cast
//  conv_fused: per 128-px tile, loop all 4 o-chunks of the 3x3 conv implicit
//    GEMM (bf16 MFMA 16x16x32, m97 structure, XOR-swizzled LDS), accumulate
//    the 18 head outputs in registers across chunks, then paired softmax +
//    direct output scatter.  No atomics, no finalize pass, no memset.
//
// Workspace layout (bytes):
//   [0,        2359296)   Wr2  bf16 [512 o][2304 k]   (B^T conv weights, k=(kh,kw,c))
//   [2359296,  2392064)   Wh2  bf16 [32 j][512 o]     (cls 0..5, box 6..17, 18..31 zero)
//   [2392064, 17100800)   (unused)
//   [17100800,123197440)  fpad bf16 padded NHWC feats (pad RINGS zeroed by
//                         prep_all; gap/overrun cells hold harmless poison ->
//                         feed only discarded outputs)
// ---------------------------------------------------------------------------

typedef __bf16 bf16x8 __attribute__((ext_vector_type(8)));
typedef float  f32x4  __attribute__((ext_vector_type(4)));

#define WS_WR2_OFF   0
#define WS_WH2_OFF   2359296
#define WS_FP_OFF    17100800

__device__ __forceinline__ unsigned short f2bf(float f) {
    unsigned u = __builtin_bit_cast(unsigned, f);
    unsigned r = (u + 0x7FFF + ((u >> 16) & 1)) >> 16;
    return (unsigned short)r;
}

__device__ __forceinline__ void gl_lds16(const void* g, void* l) {
    __builtin_amdgcn_global_load_lds(
        (const __attribute__((address_space(1))) unsigned int*)g,
        (__attribute__((address_space(3))) unsigned int*)l, 16, 0, 0);
}

// ---------------------------------------------------------------------------
// prep_all: blockIdx ranges
//   [0, 3268)        : feature cast/transpose (LDS transpose tile)
//   [3268, 4056)     : zero pad rings
//   [4056, 8728)     : weight repack
// ---------------------------------------------------------------------------
__global__ __launch_bounds__(256) void prep_all(
    const float* __restrict__ f0, const float* __restrict__ f1,
    const float* __restrict__ f2, const float* __restrict__ f3,
    const float* __restrict__ f4,
    const float* __restrict__ Wc, const float* __restrict__ Wcls,
    const float* __restrict__ Wbox,
    unsigned short* __restrict__ fpad,
    unsigned short* __restrict__ wr2, unsigned short* __restrict__ wh2)
{
    __shared__ unsigned short lds[64 * 258];
    const int blk = blockIdx.x;
    const int t = threadIdx.x;

    if (blk < 3268) {
        // ---- feature cast/transpose ----
        int bi = blk;
        int b = bi / 817;
        int r = bi - b * 817;
        const float* fsrc; int H, W, Wp, h, wb; long lb;
        if (r < 600)      { fsrc=f0; H=150; W=250; Wp=252; h=r>>2; wb=r&3; lb=32768    + (long)b*9805824; }
        else if (r < 750) { int rr=r-600; fsrc=f1; H=75; W=125; Wp=127; h=rr>>1; wb=rr&1; lb=39288832 + (long)b*2503424; }
        else if (r < 788) { fsrc=f2; H=38; W=63; Wp=65; h=r-750; wb=0; lb=49335296 + (long)b*665600; }
        else if (r < 807) { fsrc=f3; H=19; W=32; Wp=34; h=r-788; wb=0; lb=52030464 + (long)b*182784; }
        else              { fsrc=f4; H=10; W=16; Wp=18; h=r-807; wb=0; lb=52794368 + (long)b*55296; }
        const long cstr = (long)H * W;
        const int w = t & 63;
        const int wg = wb * 64 + w;
        const bool wok = (wg < W);
        const float* src = fsrc + (((long)b * 256) * H + h) * W + wg;
        unsigned* ldsw = (unsigned*)lds;
        #pragma unroll 4
        for (int it = 0; it < 32; ++it) {
            int c0 = (t >> 6) * 2 + it * 8;           // even c in [0,256)
            float v0 = wok ? src[(long)c0 * cstr] : 0.0f;
            float v1 = wok ? src[(long)(c0 + 1) * cstr] : 0.0f;
            unsigned pk = (unsigned)f2bf(v0) | ((unsigned)f2bf(v1) << 16);
            ldsw[w * 129 + (c0 >> 1)] = pk;
        }
        __syncthreads();
        #pragma unroll
        for (int k = 0; k < 8; ++k) {
            int g  = k * 256 + t;
            int px = g >> 5;
            int pg = wb * 64 + px;
            if (pg >= W) continue;
            int d0 = px * 129 + (g & 31) * 4;
            uint4 v;
            v.x = ldsw[d0]; v.y = ldsw[d0 + 1]; v.z = ldsw[d0 + 2]; v.w = ldsw[d0 + 3];
            unsigned short* dst = fpad + lb + (long)((h + 1) * Wp + (pg + 1)) * 256 + (g & 31) * 8;
            *(uint4*)dst = v;
        }
    } else if (blk < 4056) {
        // ---- zero pad rings ----
        int idx = (blk - 3268) * 256 + t;            // < 201728 = 4 * 50432
        int b = idx / 50432;
        int rem = idx - b * 50432;
        int Wp, H, W; long lb;
        if (rem < 25728)      {               Wp=252; H=150; W=250; lb=32768    + (long)b*9805824; }
        else if (rem < 38656) { rem -= 25728; Wp=127; H=75;  W=125; lb=39288832 + (long)b*2503424; }
        else if (rem < 45248) { rem -= 38656; Wp=65;  H=38;  W=63;  lb=49335296 + (long)b*665600;  }
        else if (rem < 48640) { rem -= 45248; Wp=34;  H=19;  W=32;  lb=52030464 + (long)b*182784;  }
        else                  { rem -= 48640; Wp=18;  H=10;  W=16;  lb=52794368 + (long)b*55296;   }
        int c = rem >> 5, slot = rem & 31;
        int h, w;
        if (c < Wp)          { h = 0;     w = c; }
        else if (c < 2 * Wp) { h = H + 1; w = c - Wp; }
        else {
            int c2 = c - 2 * Wp;
            h = 1 + (c2 >> 1);
            w = (c2 & 1) ? (W + 1) : 0;
        }
        uint4 z = {0u, 0u, 0u, 0u};
        *(uint4*)(fpad + lb + (long)(h * Wp + w) * 256 + slot * 8) = z;
    } else {
        // ---- weight repack ----
        int idx = (blk - 4056) * 256 + t;            // < 1196032
        if (idx < 1179648) {
            int o = idx / 2304;
            int k = idx - o * 2304;
            int r = k >> 8, c = k & 255;
            wr2[idx] = f2bf(Wc[o * 2304 + c * 9 + r]);
        } else {
            int i2 = idx - 1179648;                  // < 16384
            int j = i2 >> 9, o = i2 & 511;
            float v = (j < 6) ? Wcls[j * 512 + o]
                    : (j < 18) ? Wbox[(j - 6) * 512 + o] : 0.0f;
            wh2[j * 512 + o] = f2bf(v);
        }
    }
}

// ---------------------------------------------------------------------------
// conv_fused: grid 1596 (one block per 128-px tile). Loops chunk 0..3; each
// pass is the verified m97-style K-loop (BK=64, global_load_lds width 16,
// XOR-swizzled LDS). Head partials accumulate in acc2 registers across
// chunks; tail does bias + paired softmax + coalesced-ish output scatter.
// ---------------------------------------------------------------------------
__global__ __launch_bounds__(256) void conv_fused(
    const unsigned short* __restrict__ fpad,
    const unsigned short* __restrict__ wr2,
    const unsigned short* __restrict__ wh2,
    const float* __restrict__ b_conv,
    const float* __restrict__ b_cls,
    const float* __restrict__ b_box,
    float* __restrict__ out)
{
    __shared__ unsigned short smem[16384];   // K-loop: A[0,8K)ush B[8K,16K)ush; reused by epilogues
    const int tid = threadIdx.x;
    const int tile = blockIdx.x;             // < 1596
    int b = tile / 399;
    int tr = tile - b * 399;
    int Wp, lt, H, W, noff; long lb;
    if (tr < 296)      { lt = tr;       Wp=252; H=150; W=250; noff=0;      lb = 32768    + (long)b*9805824; }
    else if (tr < 371) { lt = tr - 296; Wp=127; H=75;  W=125; noff=112500; lb = 39288832 + (long)b*2503424; }
    else if (tr < 391) { lt = tr - 371; Wp=65;  H=38;  W=63;  noff=140625; lb = 49335296 + (long)b*665600;  }
    else if (tr < 397) { lt = tr - 391; Wp=34;  H=19;  W=32;  noff=147807; lb = 52030464 + (long)b*182784;  }
    else               { lt = tr - 397; Wp=18;  H=10;  W=16;  noff=149631; lb = 52794368 + (long)b*55296;   }

    const int arow  = tid >> 3;                       // 0..31 staging row group
    const int aslot = (tid & 7) ^ (arow & 7);         // swizzled global 16B slot
    const long apix  = lb + (long)(Wp + lt * 128 + arow) * 256 + aslot * 8;
    const long bofs0 = (long)arow * 2304 + aslot * 8;

    const int wv = tid >> 6, lane = tid & 63;
    char* lA = (char*)smem + wv * 1024;
    char* lB = (char*)smem + 16384 + wv * 1024;
    const int mrow = (wv & 1) * 64, ncol = (wv >> 1) * 64;
    const int mr = lane & 15;
    const int kq = (lane >> 4) * 8;
    const int m7 = mr & 7;

    f32x4 acc2[2][2];                                  // head accumulator, all chunks
    #pragma unroll
    for (int mi = 0; mi < 2; ++mi)
        #pragma unroll
        for (int ni = 0; ni < 2; ++ni) acc2[mi][ni] = (f32x4){0.f, 0.f, 0.f, 0.f};

    for (int chunk = 0; chunk < 4; ++chunk) {
        const unsigned short* wrc = wr2 + (long)chunk * 294912;  // chunk*128*2304
        f32x4 acc[4][4];
        #pragma unroll
        for (int mt = 0; mt < 4; ++mt)
            #pragma unroll
            for (int nt = 0; nt < 4; ++nt) acc[mt][nt] = (f32x4){0.f, 0.f, 0.f, 0.f};

        for (int r = 0; r < 9; ++r) {
            const int doff = (r / 3 - 1) * Wp + (r % 3 - 1);
            const unsigned short* ga = fpad + apix + (long)doff * 256;
            const unsigned short* gb = wrc + bofs0 + r * 256;
            for (int cb = 0; cb < 4; ++cb) {
                const unsigned short* ga2 = ga + cb * 64;
                const unsigned short* gb2 = gb + cb * 64;
                #pragma unroll
                for (int i = 0; i < 4; ++i) {
                    gl_lds16(ga2 + i * 8192,  lA + i * 4096);   // +32 pixel rows
                    gl_lds16(gb2 + i * 73728, lB + i * 4096);   // +32 o rows
                }
                __syncthreads();
                #pragma unroll
                for (int kk = 0; kk < 64; kk += 32) {
                    const int sx = ((((kk >> 3) + (lane >> 4)) ^ m7) << 3);
                    bf16x8 af[4], bfr[4];
                    #pragma unroll
                    for (int mt = 0; mt < 4; ++mt)
                        af[mt] = *(const bf16x8*)&smem[(mrow + mt * 16 + mr) * 64 + sx];
                    #pragma unroll
                    for (int nt = 0; nt < 4; ++nt)
                        bfr[nt] = *(const bf16x8*)&smem[8192 + (ncol + nt * 16 + mr) * 64 + sx];
                    #pragma unroll
                    for (int mt = 0; mt < 4; ++mt)
                        #pragma unroll
                        for (int nt = 0; nt < 4; ++nt)
                            acc[mt][nt] = __builtin_amdgcn_mfma_f32_16x16x32_bf16(
                                af[mt], bfr[nt], acc[mt][nt], 0, 0, 0);
                }
                __syncthreads();
            }
        }

        // Epilogue: bias + relu, conv1 -> LDS bf16 [128 px][128 o], XOR swizzle
        float bias[4];
        #pragma unroll
        for (int nt = 0; nt < 4; ++nt) bias[nt] = b_conv[chunk * 128 + ncol + nt * 16 + mr];
        #pragma unroll
        for (int mt = 0; mt < 4; ++mt)
            #pragma unroll
            for (int nt = 0; nt < 4; ++nt)
                #pragma unroll
                for (int q = 0; q < 4; ++q) {
                    int row = mrow + mt * 16 + (lane >> 4) * 4 + q;
                    int col = ncol + nt * 16 + mr;
                    int sl  = (col >> 3) ^ (row & 7);
                    smem[row * 128 + (sl << 3) + (col & 7)] =
                        f2bf(fmaxf(acc[mt][nt][q] + bias[nt], 0.0f));
                }
        __syncthreads();

        // Head GEMM: [128 px x 128 o] @ Wh2^T chunk -> accumulate [128 px x 32 j]
        #pragma unroll
        for (int ks = 0; ks < 4; ++ks) {
            const int sg = ks * 4 + (lane >> 4);      // logical 16B slot 0..15
            bf16x8 ha[2], hb[2];
            #pragma unroll
            for (int mi = 0; mi < 2; ++mi) {
                int rowH = (wv * 2 + mi) * 16 + mr;
                ha[mi] = *(const bf16x8*)&smem[rowH * 128 + ((sg ^ m7) << 3)];
            }
            #pragma unroll
            for (int ni = 0; ni < 2; ++ni)
                hb[ni] = *(const bf16x8*)&wh2[(ni * 16 + mr) * 512 + chunk * 128 + ks * 32 + kq];
            #pragma unroll
            for (int mi = 0; mi < 2; ++mi)
                #pragma unroll
                for (int ni = 0; ni < 2; ++ni)
                    acc2[mi][ni] = __builtin_amdgcn_mfma_f32_16x16x32_bf16(
                        ha[mi], hb[ni], acc2[mi][ni], 0, 0, 0);
        }
        __syncthreads();   // head reads done before next chunk restages smem
    }

    // acc2 -> LDS f32 [128 px][19] (odd stride: conflict-light)
    float* sf = (float*)smem;
    #pragma unroll
    for (int ni = 0; ni < 2; ++ni) {
        int j = ni * 16 + mr;
        if (j < 18) {
            #pragma unroll
            for (int mi = 0; mi < 2; ++mi)
                #pragma unroll
                for (int q = 0; q < 4; ++q) {
                    int px = (wv * 2 + mi) * 16 + (lane >> 4) * 4 + q;
                    sf[px * 19 + j] = acc2[mi][ni][q];
                }
        }
    }
    __syncthreads();

    // Tail: per-pixel bias + paired sigmoid-softmax + scatter
    if (tid < 128) {
        const int m = tid;
        const int f = Wp + lt * 128 + m;              // flat padded index
        const int hp = f / Wp, wp = f - hp * Wp;
        if (hp >= 1 && hp <= H && wp >= 1 && wp <= W) {
            const float* s = sf + m * 19;
            float sc[6], bb[12], pr[6];
            #pragma unroll
            for (int c = 0; c < 6; ++c) sc[c] = s[c] + b_cls[c];
            #pragma unroll
            for (int k = 0; k < 12; ++k) bb[k] = s[6 + k] + b_box[k];
            #pragma unroll
            for (int c = 0; c < 6; ++c) {
                int p = (c < 3) ? c + 3 : c - 3;
                pr[c] = 1.0f / (1.0f + expf(sc[p] - sc[c]));
            }
            int n = noff + ((hp - 1) * W + (wp - 1)) * 3;
            long o0 = ((long)b * 150111 + n) * 2;
            float* O0 = out + o0;
            float* O1 = out + 1200888 + o0;
            float* O2 = out + 2401776 + ((long)b * 150111 + n) * 4;
            #pragma unroll
            for (int c = 0; c < 6; ++c) { O0[c] = sc[c]; O1[c] = pr[c]; }
            #pragma unroll
            for (int k = 0; k < 12; ++k) O2[k] = bb[k];
        }
    }
}

// ---------------------------------------------------------------------------
extern "C" void kernel_launch(void* const* d_in, const int* in_sizes, int n_in,
                              void* d_out, int out_size, void* d_ws, size_t ws_size,
                              hipStream_t stream)
{
    const float* f0   = (const float*)d_in[0];
    const float* f1   = (const float*)d_in[1];
    const float* f2   = (const float*)d_in[2];
    const float* f3   = (const float*)d_in[3];
    const float* f4   = (const float*)d_in[4];
    // d_in[5] = im_info (unused by reference math)
    const float* Wc   = (const float*)d_in[6];
    const float* bC   = (const float*)d_in[7];
    const float* Wcls = (const float*)d_in[8];
    const float* bcls = (const float*)d_in[9];
    const float* Wbox = (const float*)d_in[10];
    const float* bbox = (const float*)d_in[11];

    unsigned short* wr2  = (unsigned short*)((char*)d_ws + WS_WR2_OFF);
    unsigned short* wh2  = (unsigned short*)((char*)d_ws + WS_WH2_OFF);
    unsigned short* fpad = (unsigned short*)((char*)d_ws + WS_FP_OFF);

    hipLaunchKernelGGL(prep_all, dim3(8728), dim3(256), 0, stream,
                       f0, f1, f2, f3, f4, Wc, Wcls, Wbox, fpad, wr2, wh2);
    hipLaunchKernelGGL(conv_fused, dim3(1596), dim3(256), 0, stream,
                       fpad, wr2, wh2, bC, bcls, bbox, (float*)d_out);
}